// Round 10
// baseline (72662.933 us; speedup 1.0000x reference)
//
#include <hip/hip_runtime.h>

// Echo-state network recurrence on MI355X (gfx950).
// Round-10: single-XCD team (validated r9: FETCH 2.5GB->6MB, 63.5ms) with
// SPLIT detection/data. r9's tagged-pair poll re-read 8KB x 128 waves = 1MB
// of XCD0-L2 bandwidth per sampling round (~570 cyc) — now the wall. New
// protocol: tags[2][128] (poll 8B/lane, 64KB/round, 16x less) + plain value
// buffers read ONCE after detection. Producer orders values->tag via
// vmcnt(0); consumer orders tag-check->value-read via volatile asm program
// order. Same parity-induction safety. Plain publish stores (L1 write-
// through -> shared L2), sc1 polls (L1-bypass, L2-hit) — the r9-proven combo.

#define HH    1024
#define TT    50000
#define WASH  200
#define NROLE 128   // role w owns rows [8w, 8w+8)
#define NBLK  2048
#define NT    64
#define SPIN_CAP (1u << 20)

typedef unsigned int u32;
typedef float f32x4 __attribute__((ext_vector_type(4)));
typedef int   i32x2 __attribute__((ext_vector_type(2)));

__device__ __forceinline__ float fast_tanh(float x) {
  // tanh(x) = 1 - 2/(exp2(2x*log2e)+1); safe at +/-inf.
  float e = __builtin_amdgcn_exp2f(x * 2.8853900817779268f);
  return fmaf(-2.0f, __builtin_amdgcn_rcpf(e + 1.0f), 1.0f);
}

template <int CTRL>
__device__ __forceinline__ float dpp_movf(float x) {
  return __int_as_float(__builtin_amdgcn_update_dpp(
      0, __float_as_int(x), CTRL, 0xF, 0xF, true));
}
__device__ __forceinline__ float swz_xor16(float x) {
  return __int_as_float(__builtin_amdgcn_ds_swizzle(__float_as_int(x), 0x401F));
}

#define YREDUCE()                                                         \
  { y += __shfl_xor(y, 32);                                               \
    y += swz_xor16(y);                                                    \
    y += dpp_movf<0x128>(y);   /* row_ror:8   */                          \
    y += dpp_movf<0x141>(y);   /* half mirror */                          \
    y += dpp_movf<0x1B>(y);    /* quad reverse*/                          \
    y += dpp_movf<0xB1>(y); }  /* quad xor1   */

// one-shot 64B value read (lane l -> cols 16l..16l+15), sc1 = L1-bypass
#define VAL_READ(vbase)                                                                 \
  { const float* vp = (vbase) + 16 * l;                                                 \
    asm volatile("global_load_dwordx4 %0, %1, off sc1"           : "=v"(v0) : "v"(vp)); \
    asm volatile("global_load_dwordx4 %0, %1, off offset:16 sc1" : "=v"(v1) : "v"(vp)); \
    asm volatile("global_load_dwordx4 %0, %1, off offset:32 sc1" : "=v"(v2) : "v"(vp)); \
    asm volatile("global_load_dwordx4 %0, %1, off offset:48 sc1" : "=v"(v3) : "v"(vp)); \
    asm volatile("s_waitcnt vmcnt(0)"                                                   \
                 : "+v"(v0), "+v"(v1), "+v"(v2), "+v"(v3));                             \
    xv[0]=v0.x;  xv[1]=v0.y;  xv[2]=v0.z;  xv[3]=v0.w;                                  \
    xv[4]=v1.x;  xv[5]=v1.y;  xv[6]=v1.z;  xv[7]=v1.w;                                  \
    xv[8]=v2.x;  xv[9]=v2.y;  xv[10]=v2.z; xv[11]=v2.w;                                 \
    xv[12]=v3.x; xv[13]=v3.y; xv[14]=v3.z; xv[15]=v3.w; }

__global__ __launch_bounds__(NT, 2) void esn_kernel(
    const float* __restrict__ u,
    const float* __restrict__ w_in,
    const float* __restrict__ w_res,
    const float* __restrict__ w_out,
    const int*   __restrict__ mask,
    float*       __restrict__ out,
    char*        __restrict__ ws)
{
  const int l = threadIdx.x;

  // --- team formation: XCD 0 only, first 128 claimants persist (r9-proven) ---
  u32 xcc;
  asm("s_getreg_b32 %0, hwreg(HW_REG_XCC_ID)" : "=s"(xcc));
  if (xcc != 0) return;
  int slot = 0;
  if (l == 0) slot = atomicAdd((int*)ws, 1);   // ws[0..63] zeroed each launch
  slot = __shfl(slot, 0);
  if (slot >= NROLE) return;
  const int w = slot;                          // role: rows [8w, 8w+8)

  int*   tb0 = (int*)(ws + 4096);      // tags, parity 0 (512 B)
  int*   tb1 = (int*)(ws + 5120);      // tags, parity 1
  float* vb0 = (float*)(ws + 8192);    // values, parity 0 (4 KB)
  float* vb1 = (float*)(ws + 12288);   // values, parity 1

  __shared__ float lds_c[HH];
  for (int h = l; h < HH; h += NT) lds_c[mask[h]] = w_out[h];
  __syncthreads();

  // weights resident in registers: 8 rows x 16 cols (cols 16l..16l+15)
  float wr[8][16];
#pragma unroll
  for (int row = 0; row < 8; ++row) {
    const f32x4* wp = (const f32x4*)(w_res + (size_t)(8 * w + row) * HH + 16 * l);
#pragma unroll
    for (int q = 0; q < 4; ++q) {
      f32x4 v = wp[q];
      wr[row][4*q+0] = v.x; wr[row][4*q+1] = v.y;
      wr[row][4*q+2] = v.z; wr[row][4*q+3] = v.w;
    }
  }
  const float win = w_in[8 * w + (l >> 3)];    // lane (l&7)==0 stores row 8w+(l>>3)

  float cr[16];                                // readout coeffs, cols 16l..16l+15
#pragma unroll
  for (int q = 0; q < 4; ++q) {
    f32x4 v = *(const f32x4*)(lds_c + 16 * l + 4 * q);
    cr[4*q+0] = v.x; cr[4*q+1] = v.y; cr[4*q+2] = v.z; cr[4*q+3] = v.w;
  }

  const int* tp0 = tb0 + 2 * l;                // lane l watches tags 2l, 2l+1
  const int* tp1 = tb1 + 2 * l;
  const int lb32 = l & 32, lb16 = l & 16, lb8 = l & 8;
  int dead = 0;

  for (int t = 0; t < TT; ++t) {
    const int pa = t & 1;
    const float u_t = u[t];
    float acc[8];
#pragma unroll
    for (int i = 0; i < 8; ++i) acc[i] = 0.f;
    float xv[16];
    f32x4 v0, v1, v2, v3;
    const bool doRead = ((t & 127) == w) && (t > 0);

    if (t > 0 && !dead) {
      // --- detect: poll tiny tag array until all tags >= t (signed) ---
      const int* tp = pa ? tp0 : tp1;          // tags of step t-1 in tb[(t-1)&1]
      i32x2 tg;
      u32 guard = 0;
      for (;;) {
        asm volatile("global_load_dwordx2 %0, %1, off sc1" : "=v"(tg) : "v"(tp));
        asm volatile("s_waitcnt vmcnt(0)" : "+v"(tg));
        if (__ballot((tg.x < t) | (tg.y < t)) == 0) break;
        if (++guard > SPIN_CAP) { dead = 1; break; }
      }
      // --- one-shot value read of x_{t-1} (ordered after tag check) ---
      VAL_READ(pa ? vb0 : vb1);
#pragma unroll
      for (int j = 0; j < 16; ++j)
#pragma unroll
        for (int row = 0; row < 8; ++row)
          acc[row] = fmaf(wr[row][j], xv[j], acc[row]);
    }

    // fold 64 lanes x 8 accs -> row (l>>3) sum on lanes with (l&7)==0
    float t0 = (lb32 ? acc[4] : acc[0]) + __shfl_xor(lb32 ? acc[0] : acc[4], 32);
    float t1 = (lb32 ? acc[5] : acc[1]) + __shfl_xor(lb32 ? acc[1] : acc[5], 32);
    float t2 = (lb32 ? acc[6] : acc[2]) + __shfl_xor(lb32 ? acc[2] : acc[6], 32);
    float t3 = (lb32 ? acc[7] : acc[3]) + __shfl_xor(lb32 ? acc[3] : acc[7], 32);
    float s0 = (lb16 ? t2 : t0) + swz_xor16(lb16 ? t0 : t2);
    float s1 = (lb16 ? t3 : t1) + swz_xor16(lb16 ? t1 : t3);
    float r0 = (lb8 ? s1 : s0) + dpp_movf<0x128>(lb8 ? s0 : s1);
    r0 += dpp_movf<0x141>(r0);
    r0 += dpp_movf<0x1B>(r0);
    r0 += dpp_movf<0xB1>(r0);

    float x_new = fast_tanh(fmaf(win, u_t, r0));
    // publish: 8 row values (plain stores), drain, then tag (plain store)
    {
      float* vdst = ((pa) ? vb1 : vb0) + 8 * w + (l >> 3);
      if ((l & 7) == 0)
        asm volatile("global_store_dword %0, %1, off" :: "v"(vdst), "v"(x_new));
      asm volatile("s_waitcnt vmcnt(0)");
      if (l == 0) {
        int tag = t + 1;
        int* tdst = (pa ? tb1 : tb0) + w;
        asm volatile("global_store_dword %0, %1, off" :: "v"(tdst), "v"(tag));
      }
    }

    // readout y_{t-1} from this step's values (this role's turn, off path)
    if (doRead) {
      float y = 0.f;
#pragma unroll
      for (int j = 0; j < 16; ++j) y = fmaf(cr[j], xv[j], y);
      YREDUCE();
      if (l == 0 && t - 1 >= WASH) out[t - 1 - WASH] = y;
    }
  }

  // final readout: x_{TT-1} published but never consumed in-loop (role 0)
  if (w == 0) {
    i32x2 tg;
    u32 guard = 0;
    for (;;) {                                  // step TT-1 tags live in tb[1]
      asm volatile("global_load_dwordx2 %0, %1, off sc1" : "=v"(tg) : "v"(tp1));
      asm volatile("s_waitcnt vmcnt(0)" : "+v"(tg));
      if (__ballot((tg.x < TT) | (tg.y < TT)) == 0) break;
      if (++guard > SPIN_CAP) break;
    }
    float xv[16];
    f32x4 v0, v1, v2, v3;
    VAL_READ(vb1);                              // (TT-1)&1 == 1
    float y = 0.f;
#pragma unroll
    for (int j = 0; j < 16; ++j) y = fmaf(cr[j], xv[j], y);
    YREDUCE();
    if (l == 0) out[TT - 1 - WASH] = y;
  }
}

extern "C" void kernel_launch(void* const* d_in, const int* in_sizes, int n_in,
                              void* d_out, int out_size, void* d_ws, size_t ws_size,
                              hipStream_t stream) {
  const float* u     = (const float*)d_in[0];
  const float* w_in  = (const float*)d_in[1];
  const float* w_res = (const float*)d_in[2];
  const float* w_out = (const float*)d_in[3];
  const int*   mask  = (const int*)d_in[4];
  float* out = (float*)d_out;

  // zero the role-claim counter; tag buffers rely on 0xAA poison being
  // negative (signed compare) and values are gated behind tags.
  hipMemsetAsync(d_ws, 0, 64, stream);

  esn_kernel<<<NBLK, NT, 0, stream>>>(u, w_in, w_res, w_out, mask, out,
                                      (char*)d_ws);
}